// Round 19
// baseline (901.417 us; speedup 1.0000x reference)
//
#include <hip/hip_runtime.h>

#define N_NODES 50000
#define N_EDGES 800000
#define F_IN 24
#define HDIM 128
#define N_GRAPHS 100
#define BN_EPS 1e-5f
#define NBLK 196                          // ceil(N_NODES/256)
#define ROWS_PER_GRAPH (N_NODES / N_GRAPHS)
#define MM_GRID 782                       // ceil(N_NODES/64), 64-row tiles
#define HIST_BLKS ((N_EDGES + 255) / 256) // 3125
#define PREP_BLKS (F_IN + 2 * HDIM)       // 280
#define SSTR 32                           // 32 floats = 128 B: one cache line per channel
#define SUMS_PER_LAYER (256 * SSTR)       // 8192 floats = 32 KB
#define STATS_BLKS 196                    // 256 rows/block: 196 atomics per line

typedef _Float16 h2 __attribute__((ext_vector_type(2)));   // packed fp16 pair
typedef _Float16 h4 __attribute__((ext_vector_type(4)));   // 4 fp16 = 8 B
typedef _Float16 f16x8 __attribute__((ext_vector_type(8))); // MFMA A/B frag (4 VGPR)
typedef float f32x4 __attribute__((ext_vector_type(4)));    // MFMA C/D frag

// ---------------- fused: layer-1 matmul (vector, K=24) + edge scatter ------------
// Blocks [0, 2*MM_GRID): A(fp32)=X@(Wt-Wb)+b (even) / C(fp16)=X@Wb (odd).
// Blocks [2*MM_GRID, +HIST_BLKS): atomic-free scatter ssrc[off[dst]+rank]=src.
// __launch_bounds__(256,8) caps VGPR at 64 (mm1 needs ~52 standalone) so the
// latency-bound scatter role gets 8 blocks/CU — R8's 164-VGPR fusion failure fixed.
__global__ __launch_bounds__(256, 8) void k_l1(const float* __restrict__ X,
                                               const float* __restrict__ Wcat,
                                               const float* __restrict__ bias,
                                               float* __restrict__ A, _Float16* __restrict__ C,
                                               const int* __restrict__ src,
                                               const int* __restrict__ dst,
                                               const unsigned* __restrict__ off,
                                               const unsigned* __restrict__ rank,
                                               unsigned* __restrict__ ssrc) {
    constexpr int K = F_IN, KC = F_IN;
    __shared__ float Xs[KC * 68];    // [kk][row], pad 64->68
    __shared__ float Ws[KC * 128];   // [kk][col]
    int b = blockIdx.x;
    int tid = threadIdx.x;

    if (b >= 2 * MM_GRID) {
        int e = (b - 2 * MM_GRID) * 256 + tid;
        if (e < N_EDGES)
            ssrc[off[dst[e]] + rank[e]] = (unsigned)src[e];
        return;
    }

    int row0 = (b >> 1) * 64;
    const bool isA = (b & 1) == 0;
    const int colbase = isA ? 0 : 128;
    int cg = tid & 31;
    int rg = tid >> 5;

    float acc[8][4];
#pragma unroll
    for (int ri = 0; ri < 8; ++ri)
#pragma unroll
        for (int ci = 0; ci < 4; ++ci)
            acc[ri][ci] = isA ? bias[cg * 4 + ci] : 0.f;

    for (int k0 = 0; k0 < K; k0 += KC) {
        __syncthreads();
        {
            const int C4 = KC / 4;
            for (int i = tid; i < 64 * C4; i += 256) {
                int c4 = i % C4, r = i / C4;
                int row = row0 + r;
                float4 v = make_float4(0.f, 0.f, 0.f, 0.f);
                if (row < N_NODES) v = *(const float4*)&X[row * K + k0 + c4 * 4];
                Xs[(c4 * 4 + 0) * 68 + r] = v.x;
                Xs[(c4 * 4 + 1) * 68 + r] = v.y;
                Xs[(c4 * 4 + 2) * 68 + r] = v.z;
                Xs[(c4 * 4 + 3) * 68 + r] = v.w;
            }
        }
        for (int i = tid; i < KC * 32; i += 256) {
            int c4 = i & 31, kr = i >> 5;
            *(float4*)&Ws[kr * 128 + c4 * 4] =
                *(const float4*)&Wcat[(k0 + kr) * 256 + colbase + c4 * 4];
        }
        __syncthreads();
#pragma unroll
        for (int kk = 0; kk < KC; ++kk) {
            float4 t0 = *(const float4*)&Xs[kk * 68 + rg * 8];
            float4 t1 = *(const float4*)&Xs[kk * 68 + rg * 8 + 4];
            float4 w = *(const float4*)&Ws[kk * 128 + cg * 4];
            float t[8] = {t0.x, t0.y, t0.z, t0.w, t1.x, t1.y, t1.z, t1.w};
            float wv[4] = {w.x, w.y, w.z, w.w};
#pragma unroll
            for (int ri = 0; ri < 8; ++ri)
#pragma unroll
                for (int ci = 0; ci < 4; ++ci)
                    acc[ri][ci] += t[ri] * wv[ci];
        }
    }

#pragma unroll
    for (int ri = 0; ri < 8; ++ri) {
        int row = row0 + rg * 8 + ri;
        if (row < N_NODES) {
            if (isA) {
                *(float4*)&A[row * HDIM + cg * 4] =
                    make_float4(acc[ri][0], acc[ri][1], acc[ri][2], acc[ri][3]);
            } else {
                union { h2 h[2]; uint2 u; } pk;
                pk.h[0] = h2{(_Float16)acc[ri][0], (_Float16)acc[ri][1]};
                pk.h[1] = h2{(_Float16)acc[ri][2], (_Float16)acc[ri][3]};
                *(uint2*)&C[row * HDIM + cg * 4] = pk.u;
            }
        }
    }
}

// ---------------- layers 2/3: MFMA matmul (fp16 h in, fp32 acc) ------------------
// BN scale/shift derived in-block from previous dispatch's sums (plain loads;
// kernel-boundary acquire gives cross-XCD visibility — NO in-kernel device fence,
// which costs ~40 us/kernel-wide use on gfx950 [measured R12->R13]).
__global__ __launch_bounds__(256) void k_mmf(const _Float16* __restrict__ X,   // h, fp16
                                             const _Float16* __restrict__ Wf, // 2 planes x 16384, frag-linear
                                             const float* __restrict__ bias,
                                             const float* __restrict__ sums,  // padded stats
                                             const float* __restrict__ g,
                                             const float* __restrict__ be,
                                             float* __restrict__ A, _Float16* __restrict__ C) {
    __shared__ _Float16 Xh[16 * 520];      // 16 frags x 1040 B
    __shared__ _Float16 Wh[128 * 128];     // 32 KB
    __shared__ float scs[128], shs[128];
    int tid = threadIdx.x;
    int lane = tid & 63, wv = tid >> 6;
    int row0 = blockIdx.x * 64;
    const bool isA = (blockIdx.y == 0);
    const _Float16* Wsrc = Wf + (isA ? 0 : 16384);

    if (tid < 128) {
        float S  = sums[tid * SSTR];
        float S2 = sums[(128 + tid) * SSTR];
        float mean = S / (float)N_NODES;
        float var = fmaxf(S2 / (float)N_NODES - mean * mean, 0.f);
        float scv = g[tid] / sqrtf(var + BN_EPS);
        scs[tid] = scv;
        shs[tid] = be[tid] - mean * scv;
    }
    {
        const uint4* s = (const uint4*)Wsrc;
        uint4* d = (uint4*)Wh;
        for (int i = tid; i < 2048; i += 256) d[i] = s[i];
    }
    __syncthreads();
    for (int i = tid; i < 64 * 32; i += 256) {
        int k4 = i & 31, rl = i >> 5;
        int row = row0 + rl;
        float4 v = make_float4(0.f, 0.f, 0.f, 0.f);
        if (row < N_NODES) {
            h4 xv = *(const h4*)&X[row * HDIM + k4 * 4];
            v = make_float4((float)xv.x, (float)xv.y, (float)xv.z, (float)xv.w);
        }
        int c = k4 * 4;
        v.x = fmaxf(v.x * scs[c + 0] + shs[c + 0], 0.f);
        v.y = fmaxf(v.y * scs[c + 1] + shs[c + 1], 0.f);
        v.z = fmaxf(v.z * scs[c + 2] + shs[c + 2], 0.f);
        v.w = fmaxf(v.w * scs[c + 3] + shs[c + 3], 0.f);
        int rt = rl >> 4, m = rl & 15, kc = k4 >> 3, q = (k4 >> 1) & 3, jh = k4 & 1;
        _Float16* d = Xh + (rt * 4 + kc) * 520 + (q * 16 + m) * 8 + jh * 4;
        d[0] = (_Float16)v.x; d[1] = (_Float16)v.y;
        d[2] = (_Float16)v.z; d[3] = (_Float16)v.w;
    }
    __syncthreads();

    int n = lane & 15, q = lane >> 4;
    f32x4 acc[8];
#pragma unroll
    for (int nt = 0; nt < 8; ++nt) {
        float b0 = isA ? bias[nt * 16 + n] : 0.f;
        acc[nt] = f32x4{b0, b0, b0, b0};
    }
#pragma unroll
    for (int kc = 0; kc < 4; ++kc) {
        f16x8 a = *(const f16x8*)(Xh + (wv * 4 + kc) * 520 + lane * 8);
#pragma unroll
        for (int nt = 0; nt < 8; ++nt) {
            f16x8 b = *(const f16x8*)(Wh + ((nt * 4 + kc) * 64 + lane) * 8);
            acc[nt] = __builtin_amdgcn_mfma_f32_16x16x32_f16(a, b, acc[nt], 0, 0, 0);
        }
    }
#pragma unroll
    for (int nt = 0; nt < 8; ++nt) {
#pragma unroll
        for (int r = 0; r < 4; ++r) {
            int row = row0 + wv * 16 + q * 4 + r;
            if (row < N_NODES) {
                int col = nt * 16 + n;
                if (isA) A[row * HDIM + col] = acc[nt][r];
                else     C[row * HDIM + col] = (_Float16)acc[nt][r];
            }
        }
    }
}

// ---------------- fused: weight prep + degree histogram (rank recorded) ----------
__global__ void k_pre(const float* __restrict__ W1, const float* __restrict__ W2,
                      const float* __restrict__ W3, float* __restrict__ Wcat1,
                      _Float16* __restrict__ Wf2, _Float16* __restrict__ Wf3,
                      const int* __restrict__ dst, unsigned* __restrict__ deg,
                      unsigned* __restrict__ rank) {
    int b = blockIdx.x;
    int j = threadIdx.x;
    if (b < F_IN) {
        float wb = W1[(b + F_IN) * HDIM + (j & 127)];
        float wt = W1[b * HDIM + (j & 127)];
        Wcat1[b * 256 + j] = (j < HDIM) ? (wt - wb) : wb;
    } else if (b < PREP_BLKS) {
        int idx = b - F_IN;
        int layer = idx >> 7;
        int k = idx & 127;
        const float* W = layer ? W3 : W2;
        _Float16* Wf   = layer ? Wf3 : Wf2;
        int col = j & 127;
        float wt = W[k * HDIM + col];
        float wb = W[(k + HDIM) * HDIM + col];
        float v = (j < 128) ? (wt - wb) : wb;
        int plane = j >> 7;
        int nt = col >> 4, n = col & 15, kc = k >> 5, q = (k >> 3) & 3, jj = k & 7;
        int f = ((nt * 4 + kc) * 4 + q) * 128 + n * 8 + jj;
        Wf[plane * 16384 + f] = (_Float16)v;
    } else {
        int e = (b - PREP_BLKS) * 256 + j;
        if (e < N_EDGES) rank[e] = atomicAdd(&deg[dst[e]], 1u);
    }
}

// ---------------- single-kernel scan ---------------------------------------------
__global__ __launch_bounds__(256) void k_scanall(const unsigned* __restrict__ deg,
                                                 unsigned* __restrict__ bsum,  // zeroed
                                                 unsigned* __restrict__ off) {
    __shared__ unsigned s[256];
    int t = threadIdx.x;
    int b = blockIdx.x;
    int i = b * 256 + t;
    unsigned v = (i < N_NODES) ? deg[i] : 0u;
    s[t] = v;
    __syncthreads();
    for (int d = 1; d < 256; d <<= 1) {
        unsigned u = (t >= d) ? s[t - d] : 0u;
        __syncthreads();
        s[t] += u;
        __syncthreads();
    }
    unsigned locex = s[t] - v;
    if (t == 255) atomicExch(&bsum[b], s[255] + 1u);
    __syncthreads();
    unsigned bs = 0;
    if (t < NBLK) {
        unsigned x;
        do { x = atomicAdd(&bsum[t], 0u); } while (x == 0u);
        bs = x - 1u;
    }
    s[t] = (t < NBLK) ? bs : 0u;
    __syncthreads();
    for (int d = 1; d < 256; d <<= 1) {
        unsigned u = (t >= d) ? s[t - d] : 0u;
        __syncthreads();
        s[t] += u;
        __syncthreads();
    }
    unsigned bexcl = (b == 0) ? 0u : s[b - 1];
    if (i < N_NODES) off[i] = bexcl + locex;
}

// ---------------- aggregation: flat 8-deep gather; h written as fp16 -------------
__global__ __launch_bounds__(256) void k_agg(const float* __restrict__ A,
                                             const h2* __restrict__ Cc,   // 64 h2/row
                                             const unsigned* __restrict__ off,
                                             const unsigned* __restrict__ deg,
                                             const unsigned* __restrict__ ssrc,
                                             h2* __restrict__ H) {         // 64 h2/row
    __shared__ unsigned sl[4][64];
    int w = threadIdx.x >> 6;
    int lane = threadIdx.x & 63;
    int i = blockIdx.x * 4 + w;
    int d = (int)deg[i];
    unsigned o = off[i];
    union { unsigned short us[2]; h2 v; } ninf;
    ninf.us[0] = 0xFC00; ninf.us[1] = 0xFC00;
    h2 m2 = ninf.v;
    for (int base = 0; base < d; base += 64) {
        int cntc = min(64, d - base);
        if (lane < cntc) sl[w][lane] = ssrc[o + base + lane];
        int e = 0;
        for (; e + 8 <= cntc; e += 8) {
            unsigned s0 = sl[w][e + 0], s1 = sl[w][e + 1], s2 = sl[w][e + 2], s3 = sl[w][e + 3];
            unsigned s4 = sl[w][e + 4], s5 = sl[w][e + 5], s6 = sl[w][e + 6], s7 = sl[w][e + 7];
            h2 v0 = Cc[s0 * 64 + lane];
            h2 v1 = Cc[s1 * 64 + lane];
            h2 v2 = Cc[s2 * 64 + lane];
            h2 v3 = Cc[s3 * 64 + lane];
            h2 v4 = Cc[s4 * 64 + lane];
            h2 v5 = Cc[s5 * 64 + lane];
            h2 v6 = Cc[s6 * 64 + lane];
            h2 v7 = Cc[s7 * 64 + lane];
            h2 a0 = __builtin_elementwise_max(v0, v1);
            h2 a1 = __builtin_elementwise_max(v2, v3);
            h2 a2 = __builtin_elementwise_max(v4, v5);
            h2 a3 = __builtin_elementwise_max(v6, v7);
            h2 b0 = __builtin_elementwise_max(a0, a1);
            h2 b1 = __builtin_elementwise_max(a2, a3);
            m2 = __builtin_elementwise_max(m2, __builtin_elementwise_max(b0, b1));
        }
        if (e + 4 <= cntc) {
            unsigned s0 = sl[w][e + 0], s1 = sl[w][e + 1], s2 = sl[w][e + 2], s3 = sl[w][e + 3];
            h2 v0 = Cc[s0 * 64 + lane];
            h2 v1 = Cc[s1 * 64 + lane];
            h2 v2 = Cc[s2 * 64 + lane];
            h2 v3 = Cc[s3 * 64 + lane];
            h2 a0 = __builtin_elementwise_max(v0, v1);
            h2 a1 = __builtin_elementwise_max(v2, v3);
            m2 = __builtin_elementwise_max(m2, __builtin_elementwise_max(a0, a1));
            e += 4;
        }
        for (; e < cntc; ++e)
            m2 = __builtin_elementwise_max(m2, Cc[sl[w][e] * 64 + lane]);
    }
    float2 a = *(const float2*)&A[i * HDIM + lane * 2];
    float hx = (d > 0) ? fmaxf(a.x + (float)m2.x, 0.f) : 0.f;
    float hy = (d > 0) ? fmaxf(a.y + (float)m2.y, 0.f) : 0.f;
    H[i * 64 + lane] = h2{(_Float16)hx, (_Float16)hy};
}

// ---------------- BN stats over fp16 h: 196 blocks, fp32 accumulate --------------
__global__ __launch_bounds__(256) void k_stats(const _Float16* __restrict__ H,
                                               float* __restrict__ sums) {  // zeroed, padded
    __shared__ float4 ls[256], ls2[256];
    int t = threadIdx.x;
    int c4 = t & 31, rg = t >> 5;
    int row0 = blockIdx.x * 256;
    float4 s = make_float4(0.f, 0.f, 0.f, 0.f);
    float4 s2 = make_float4(0.f, 0.f, 0.f, 0.f);
#pragma unroll 4
    for (int it = 0; it < 32; ++it) {
        int row = row0 + rg * 32 + it;
        if (row < N_NODES) {
            h4 hv = *(const h4*)&H[row * HDIM + c4 * 4];
            float4 v = make_float4((float)hv.x, (float)hv.y, (float)hv.z, (float)hv.w);
            s.x += v.x; s.y += v.y; s.z += v.z; s.w += v.w;
            s2.x += v.x * v.x; s2.y += v.y * v.y; s2.z += v.z * v.z; s2.w += v.w * v.w;
        }
    }
    ls[t] = s; ls2[t] = s2;
    __syncthreads();
    if (t < 32) {
        float4 a = ls[t], a2 = ls2[t];
#pragma unroll
        for (int j = 1; j < 8; ++j) {
            float4 b = ls[j * 32 + t], b2 = ls2[j * 32 + t];
            a.x += b.x; a.y += b.y; a.z += b.z; a.w += b.w;
            a2.x += b2.x; a2.y += b2.y; a2.z += b2.z; a2.w += b2.w;
        }
        int c = t * 4;
        atomicAdd(&sums[(c + 0) * SSTR], a.x);
        atomicAdd(&sums[(c + 1) * SSTR], a.y);
        atomicAdd(&sums[(c + 2) * SSTR], a.z);
        atomicAdd(&sums[(c + 3) * SSTR], a.w);
        atomicAdd(&sums[(128 + c + 0) * SSTR], a2.x);
        atomicAdd(&sums[(128 + c + 1) * SSTR], a2.y);
        atomicAdd(&sums[(128 + c + 2) * SSTR], a2.z);
        atomicAdd(&sums[(128 + c + 3) * SSTR], a2.w);
    }
}

// ---------------- per-graph sums + layer-3 BN stats in ONE h pass ----------------
__global__ __launch_bounds__(128) void k_poolsum(const _Float16* __restrict__ H,
                                                 float* __restrict__ Pg,     // [100][128]
                                                 float* __restrict__ sums) { // zeroed, padded
    int g = blockIdx.x;
    int k = threadIdx.x;
    const _Float16* base = H + (size_t)g * ROWS_PER_GRAPH * HDIM;
    float s = 0.f, s2 = 0.f;
#pragma unroll 4
    for (int r = 0; r < ROWS_PER_GRAPH; ++r) {
        float v = (float)base[r * HDIM + k];
        s += v; s2 += v * v;
    }
    Pg[g * HDIM + k] = s;
    atomicAdd(&sums[k * SSTR], s);
    atomicAdd(&sums[(128 + k) * SSTR], s2);
}

// ---------------- final: BN3 (from sums) + linear + relu, 1 block/graph ----------
__global__ __launch_bounds__(128) void k_out(const float* __restrict__ Pg,
                                             const float* __restrict__ sums,
                                             const float* __restrict__ g3,
                                             const float* __restrict__ be3,
                                             const float* __restrict__ Wl,
                                             const float* __restrict__ bl,
                                             float* __restrict__ out) {
    int g = blockIdx.x;
    int k = threadIdx.x;
    float S  = sums[k * SSTR];
    float S2 = sums[(128 + k) * SSTR];
    float mean = S / (float)N_NODES;
    float var = fmaxf(S2 / (float)N_NODES - mean * mean, 0.f);
    float scv = g3[k] / sqrtf(var + BN_EPS);
    float shv = be3[k] - mean * scv;
    float p = (scv * (Pg[g * HDIM + k] * (1.f / (float)ROWS_PER_GRAPH)) + shv) * Wl[k];
    __shared__ float red[2];
    for (int o = 32; o > 0; o >>= 1) p += __shfl_down(p, o);
    if ((k & 63) == 0) red[k >> 6] = p;
    __syncthreads();
    if (k == 0) out[g] = fmaxf(red[0] + red[1] + bl[0], 0.f);
}

// ---------------- launcher --------------------------------------------------------
extern "C" void kernel_launch(void* const* d_in, const int* in_sizes, int n_in,
                              void* d_out, int out_size, void* d_ws, size_t ws_size,
                              hipStream_t stream) {
    const float* x   = (const float*)d_in[0];
    const int* ei    = (const int*)d_in[1];
    const float* W1  = (const float*)d_in[3];
    const float* b1  = (const float*)d_in[4];
    const float* W2  = (const float*)d_in[5];
    const float* b2  = (const float*)d_in[6];
    const float* W3  = (const float*)d_in[7];
    const float* b3  = (const float*)d_in[8];
    const float* g1  = (const float*)d_in[9];
    const float* be1 = (const float*)d_in[10];
    const float* g2  = (const float*)d_in[11];
    const float* be2 = (const float*)d_in[12];
    const float* g3  = (const float*)d_in[13];
    const float* be3 = (const float*)d_in[14];
    const float* Wl  = (const float*)d_in[15];
    const float* bl  = (const float*)d_in[16];
    float* out = (float*)d_out;

    const int* srcp = ei;
    const int* dstp = ei + N_EDGES;

    // ---- workspace carve-up (256B aligned) ----
    char* ws = (char*)d_ws;
    size_t o = 0;
    auto alloc = [&](size_t bytes) -> void* {
        o = (o + 255) & ~(size_t)255;
        void* p = ws + o;
        o += bytes;
        return p;
    };
    float* A      = (float*)alloc((size_t)N_NODES * HDIM * 4);
    _Float16* C   = (_Float16*)alloc((size_t)N_NODES * HDIM * 2);
    _Float16* h   = (_Float16*)alloc((size_t)N_NODES * HDIM * 2);
    float* Wcat1  = (float*)alloc((size_t)F_IN * 256 * 4);
    _Float16* Wf2 = (_Float16*)alloc((size_t)2 * 16384 * 2);
    _Float16* Wf3 = (_Float16*)alloc((size_t)2 * 16384 * 2);
    // ---- zeroed region: deg .. sums (single memset) ----
    unsigned* deg  = (unsigned*)alloc((size_t)N_NODES * 4);
    unsigned* bsum = (unsigned*)alloc((size_t)NBLK * 4);
    float* sums    = (float*)alloc((size_t)3 * SUMS_PER_LAYER * 4);  // 96 KB padded
    // ---- not zeroed (fully overwritten before read) ----
    unsigned* off  = (unsigned*)alloc((size_t)N_NODES * 4);
    unsigned* rank = (unsigned*)alloc((size_t)N_EDGES * 4);
    unsigned* ssrc = (unsigned*)alloc((size_t)N_EDGES * 4);
    float* Pg      = (float*)alloc((size_t)N_GRAPHS * HDIM * 4);
    (void)ws_size; (void)n_in; (void)in_sizes; (void)out_size;

    float* sums0 = sums;
    float* sums1 = sums + SUMS_PER_LAYER;
    float* sums2 = sums + 2 * SUMS_PER_LAYER;

    size_t zlen = (size_t)((char*)(sums + 3 * SUMS_PER_LAYER) - (char*)deg);
    (void)hipMemsetAsync(deg, 0, zlen, stream);                        // 1

    k_pre<<<PREP_BLKS + HIST_BLKS, 256, 0, stream>>>(W1, W2, W3, Wcat1, Wf2, Wf3,
                                                     dstp, deg, rank); // 2
    k_scanall<<<NBLK, 256, 0, stream>>>(deg, bsum, off);               // 3

    const dim3 MMG(MM_GRID, 2);
    const int AGB = N_NODES / 4;

    // layer 1 matmul fused with edge scatter (independent roles, 64-VGPR cap)
    k_l1<<<2 * MM_GRID + HIST_BLKS, 256, 0, stream>>>(x, Wcat1, b1, A, C,
                                                      srcp, dstp, off, rank, ssrc); // 4
    k_agg<<<AGB, 256, 0, stream>>>(A, (const h2*)C, off, deg, ssrc, (h2*)h);        // 5
    k_stats<<<STATS_BLKS, 256, 0, stream>>>(h, sums0);                              // 6

    // layer 2 (MFMA, BN1 derived in-block from sums0)
    k_mmf<<<MMG, 256, 0, stream>>>(h, Wf2, b2, sums0, g1, be1, A, C);               // 7
    k_agg<<<AGB, 256, 0, stream>>>(A, (const h2*)C, off, deg, ssrc, (h2*)h);        // 8
    k_stats<<<STATS_BLKS, 256, 0, stream>>>(h, sums1);                              // 9

    // layer 3 (MFMA, BN2 derived in-block from sums1)
    k_mmf<<<MMG, 256, 0, stream>>>(h, Wf3, b3, sums1, g2, be2, A, C);               // 10
    k_agg<<<AGB, 256, 0, stream>>>(A, (const h2*)C, off, deg, ssrc, (h2*)h);        // 11

    // per-graph pool sums + layer-3 stats in one h pass, then per-graph output
    k_poolsum<<<N_GRAPHS, 128, 0, stream>>>(h, Pg, sums2);                          // 12
    k_out<<<N_GRAPHS, 128, 0, stream>>>(Pg, sums2, g3, be3, Wl, bl, out);           // 13
}

// Round 20
// 398.347 us; speedup vs baseline: 2.2629x; 2.2629x over previous
//
#include <hip/hip_runtime.h>

#define N_NODES 50000
#define N_EDGES 800000
#define F_IN 24
#define HDIM 128
#define N_GRAPHS 100
#define BN_EPS 1e-5f
#define NBLK 196                          // ceil(N_NODES/256)
#define ROWS_PER_GRAPH (N_NODES / N_GRAPHS)
#define MM_GRID 782                       // ceil(N_NODES/64), 64-row tiles
#define HIST_BLKS ((N_EDGES + 255) / 256) // 3125
#define PREP_BLKS (F_IN + 2 * HDIM)       // 280
#define SSTR 32                           // 32 floats = 128 B: one cache line per channel
#define SUMS_PER_LAYER (256 * SSTR)       // 8192 floats = 32 KB
#define STATS_BLKS 196                    // 256 rows/block: 196 atomics per line

typedef _Float16 h2 __attribute__((ext_vector_type(2)));   // packed fp16 pair
typedef _Float16 h4 __attribute__((ext_vector_type(4)));   // 4 fp16 = 8 B
typedef _Float16 f16x8 __attribute__((ext_vector_type(8))); // MFMA A/B frag (4 VGPR)
typedef float f32x4 __attribute__((ext_vector_type(4)));    // MFMA C/D frag

// ---------------- layer-1 matmul (vector, K=24) -----------------------------------
// A(fp32) = X@(Wt-Wb)+b when y==0; C(fp16) = X@Wb when y==1. X is the fp32 input x.
// NOTE: do NOT fuse scatter into this kernel. R8 (no VGPR cap): scatter starved at
// 3 blocks/CU. R19 (launch_bounds(256,8) cap): mm spilled (1.8 GB scratch traffic).
template <int K, int KC>
__global__ __launch_bounds__(256) void k_mm1(const float* __restrict__ X,
                                             const float* __restrict__ Wcat,
                                             const float* __restrict__ bias,
                                             float* __restrict__ A, _Float16* __restrict__ C) {
    __shared__ float Xs[KC * 68];    // [kk][row], pad 64->68
    __shared__ float Ws[KC * 128];   // [kk][col]
    int tid = threadIdx.x;
    int row0 = blockIdx.x * 64;
    const bool isA = (blockIdx.y == 0);
    const int colbase = isA ? 0 : 128;
    int cg = tid & 31;
    int rg = tid >> 5;

    float acc[8][4];
#pragma unroll
    for (int ri = 0; ri < 8; ++ri)
#pragma unroll
        for (int ci = 0; ci < 4; ++ci)
            acc[ri][ci] = isA ? bias[cg * 4 + ci] : 0.f;

    for (int k0 = 0; k0 < K; k0 += KC) {
        __syncthreads();
        {
            const int C4 = KC / 4;
            for (int i = tid; i < 64 * C4; i += 256) {
                int c4 = i % C4, r = i / C4;
                int row = row0 + r;
                float4 v = make_float4(0.f, 0.f, 0.f, 0.f);
                if (row < N_NODES) v = *(const float4*)&X[row * K + k0 + c4 * 4];
                Xs[(c4 * 4 + 0) * 68 + r] = v.x;
                Xs[(c4 * 4 + 1) * 68 + r] = v.y;
                Xs[(c4 * 4 + 2) * 68 + r] = v.z;
                Xs[(c4 * 4 + 3) * 68 + r] = v.w;
            }
        }
        for (int i = tid; i < KC * 32; i += 256) {
            int c4 = i & 31, kr = i >> 5;
            *(float4*)&Ws[kr * 128 + c4 * 4] =
                *(const float4*)&Wcat[(k0 + kr) * 256 + colbase + c4 * 4];
        }
        __syncthreads();
#pragma unroll
        for (int kk = 0; kk < KC; ++kk) {
            float4 t0 = *(const float4*)&Xs[kk * 68 + rg * 8];
            float4 t1 = *(const float4*)&Xs[kk * 68 + rg * 8 + 4];
            float4 w = *(const float4*)&Ws[kk * 128 + cg * 4];
            float t[8] = {t0.x, t0.y, t0.z, t0.w, t1.x, t1.y, t1.z, t1.w};
            float wv[4] = {w.x, w.y, w.z, w.w};
#pragma unroll
            for (int ri = 0; ri < 8; ++ri)
#pragma unroll
                for (int ci = 0; ci < 4; ++ci)
                    acc[ri][ci] += t[ri] * wv[ci];
        }
    }

#pragma unroll
    for (int ri = 0; ri < 8; ++ri) {
        int row = row0 + rg * 8 + ri;
        if (row < N_NODES) {
            if (isA) {
                *(float4*)&A[row * HDIM + cg * 4] =
                    make_float4(acc[ri][0], acc[ri][1], acc[ri][2], acc[ri][3]);
            } else {
                union { h2 h[2]; uint2 u; } pk;
                pk.h[0] = h2{(_Float16)acc[ri][0], (_Float16)acc[ri][1]};
                pk.h[1] = h2{(_Float16)acc[ri][2], (_Float16)acc[ri][3]};
                *(uint2*)&C[row * HDIM + cg * 4] = pk.u;
            }
        }
    }
}

// ---------------- layers 2/3: MFMA matmul (fp16 h in, fp32 acc) ------------------
// BN scale/shift derived in-block from previous dispatch's sums (plain loads;
// kernel-boundary acquire gives cross-XCD visibility — NO in-kernel device fence,
// which costs ~40 us/kernel-wide use on gfx950 [measured R12->R13]).
__global__ __launch_bounds__(256) void k_mmf(const _Float16* __restrict__ X,   // h, fp16
                                             const _Float16* __restrict__ Wf, // 2 planes x 16384, frag-linear
                                             const float* __restrict__ bias,
                                             const float* __restrict__ sums,  // padded stats
                                             const float* __restrict__ g,
                                             const float* __restrict__ be,
                                             float* __restrict__ A, _Float16* __restrict__ C) {
    __shared__ _Float16 Xh[16 * 520];      // 16 frags x 1040 B
    __shared__ _Float16 Wh[128 * 128];     // 32 KB
    __shared__ float scs[128], shs[128];
    int tid = threadIdx.x;
    int lane = tid & 63, wv = tid >> 6;
    int row0 = blockIdx.x * 64;
    const bool isA = (blockIdx.y == 0);
    const _Float16* Wsrc = Wf + (isA ? 0 : 16384);

    if (tid < 128) {
        float S  = sums[tid * SSTR];
        float S2 = sums[(128 + tid) * SSTR];
        float mean = S / (float)N_NODES;
        float var = fmaxf(S2 / (float)N_NODES - mean * mean, 0.f);
        float scv = g[tid] / sqrtf(var + BN_EPS);
        scs[tid] = scv;
        shs[tid] = be[tid] - mean * scv;
    }
    {
        const uint4* s = (const uint4*)Wsrc;
        uint4* d = (uint4*)Wh;
        for (int i = tid; i < 2048; i += 256) d[i] = s[i];
    }
    __syncthreads();
    for (int i = tid; i < 64 * 32; i += 256) {
        int k4 = i & 31, rl = i >> 5;
        int row = row0 + rl;
        float4 v = make_float4(0.f, 0.f, 0.f, 0.f);
        if (row < N_NODES) {
            h4 xv = *(const h4*)&X[row * HDIM + k4 * 4];
            v = make_float4((float)xv.x, (float)xv.y, (float)xv.z, (float)xv.w);
        }
        int c = k4 * 4;
        v.x = fmaxf(v.x * scs[c + 0] + shs[c + 0], 0.f);
        v.y = fmaxf(v.y * scs[c + 1] + shs[c + 1], 0.f);
        v.z = fmaxf(v.z * scs[c + 2] + shs[c + 2], 0.f);
        v.w = fmaxf(v.w * scs[c + 3] + shs[c + 3], 0.f);
        int rt = rl >> 4, m = rl & 15, kc = k4 >> 3, q = (k4 >> 1) & 3, jh = k4 & 1;
        _Float16* d = Xh + (rt * 4 + kc) * 520 + (q * 16 + m) * 8 + jh * 4;
        d[0] = (_Float16)v.x; d[1] = (_Float16)v.y;
        d[2] = (_Float16)v.z; d[3] = (_Float16)v.w;
    }
    __syncthreads();

    int n = lane & 15, q = lane >> 4;
    f32x4 acc[8];
#pragma unroll
    for (int nt = 0; nt < 8; ++nt) {
        float b0 = isA ? bias[nt * 16 + n] : 0.f;
        acc[nt] = f32x4{b0, b0, b0, b0};
    }
#pragma unroll
    for (int kc = 0; kc < 4; ++kc) {
        f16x8 a = *(const f16x8*)(Xh + (wv * 4 + kc) * 520 + lane * 8);
#pragma unroll
        for (int nt = 0; nt < 8; ++nt) {
            f16x8 b = *(const f16x8*)(Wh + ((nt * 4 + kc) * 64 + lane) * 8);
            acc[nt] = __builtin_amdgcn_mfma_f32_16x16x32_f16(a, b, acc[nt], 0, 0, 0);
        }
    }
#pragma unroll
    for (int nt = 0; nt < 8; ++nt) {
#pragma unroll
        for (int r = 0; r < 4; ++r) {
            int row = row0 + wv * 16 + q * 4 + r;
            if (row < N_NODES) {
                int col = nt * 16 + n;
                if (isA) A[row * HDIM + col] = acc[nt][r];
                else     C[row * HDIM + col] = (_Float16)acc[nt][r];
            }
        }
    }
}

// ---------------- fused: weight prep + degree histogram (rank recorded) ----------
__global__ void k_pre(const float* __restrict__ W1, const float* __restrict__ W2,
                      const float* __restrict__ W3, float* __restrict__ Wcat1,
                      _Float16* __restrict__ Wf2, _Float16* __restrict__ Wf3,
                      const int* __restrict__ dst, unsigned* __restrict__ deg,
                      unsigned* __restrict__ rank) {
    int b = blockIdx.x;
    int j = threadIdx.x;
    if (b < F_IN) {
        float wb = W1[(b + F_IN) * HDIM + (j & 127)];
        float wt = W1[b * HDIM + (j & 127)];
        Wcat1[b * 256 + j] = (j < HDIM) ? (wt - wb) : wb;
    } else if (b < PREP_BLKS) {
        int idx = b - F_IN;
        int layer = idx >> 7;
        int k = idx & 127;
        const float* W = layer ? W3 : W2;
        _Float16* Wf   = layer ? Wf3 : Wf2;
        int col = j & 127;
        float wt = W[k * HDIM + col];
        float wb = W[(k + HDIM) * HDIM + col];
        float v = (j < 128) ? (wt - wb) : wb;
        int plane = j >> 7;
        int nt = col >> 4, n = col & 15, kc = k >> 5, q = (k >> 3) & 3, jj = k & 7;
        int f = ((nt * 4 + kc) * 4 + q) * 128 + n * 8 + jj;
        Wf[plane * 16384 + f] = (_Float16)v;
    } else {
        int e = (b - PREP_BLKS) * 256 + j;
        if (e < N_EDGES) rank[e] = atomicAdd(&deg[dst[e]], 1u);
    }
}

// ---------------- single-kernel scan ---------------------------------------------
__global__ __launch_bounds__(256) void k_scanall(const unsigned* __restrict__ deg,
                                                 unsigned* __restrict__ bsum,  // zeroed
                                                 unsigned* __restrict__ off) {
    __shared__ unsigned s[256];
    int t = threadIdx.x;
    int b = blockIdx.x;
    int i = b * 256 + t;
    unsigned v = (i < N_NODES) ? deg[i] : 0u;
    s[t] = v;
    __syncthreads();
    for (int d = 1; d < 256; d <<= 1) {
        unsigned u = (t >= d) ? s[t - d] : 0u;
        __syncthreads();
        s[t] += u;
        __syncthreads();
    }
    unsigned locex = s[t] - v;
    if (t == 255) atomicExch(&bsum[b], s[255] + 1u);
    __syncthreads();
    unsigned bs = 0;
    if (t < NBLK) {
        unsigned x;
        do { x = atomicAdd(&bsum[t], 0u); } while (x == 0u);
        bs = x - 1u;
    }
    s[t] = (t < NBLK) ? bs : 0u;
    __syncthreads();
    for (int d = 1; d < 256; d <<= 1) {
        unsigned u = (t >= d) ? s[t - d] : 0u;
        __syncthreads();
        s[t] += u;
        __syncthreads();
    }
    unsigned bexcl = (b == 0) ? 0u : s[b - 1];
    if (i < N_NODES) off[i] = bexcl + locex;
}

// ---------------- atomic-free scatter --------------------------------------------
__global__ void k_scatter(const int* __restrict__ src, const int* __restrict__ dst,
                          const unsigned* __restrict__ off, const unsigned* __restrict__ rank,
                          unsigned* __restrict__ ssrc) {
    int e = blockIdx.x * 256 + threadIdx.x;
    if (e < N_EDGES)
        ssrc[off[dst[e]] + rank[e]] = (unsigned)src[e];
}

// ---------------- aggregation: flat 8-deep gather; h written as fp16 -------------
__global__ __launch_bounds__(256) void k_agg(const float* __restrict__ A,
                                             const h2* __restrict__ Cc,   // 64 h2/row
                                             const unsigned* __restrict__ off,
                                             const unsigned* __restrict__ deg,
                                             const unsigned* __restrict__ ssrc,
                                             h2* __restrict__ H) {         // 64 h2/row
    __shared__ unsigned sl[4][64];
    int w = threadIdx.x >> 6;
    int lane = threadIdx.x & 63;
    int i = blockIdx.x * 4 + w;
    int d = (int)deg[i];
    unsigned o = off[i];
    union { unsigned short us[2]; h2 v; } ninf;
    ninf.us[0] = 0xFC00; ninf.us[1] = 0xFC00;
    h2 m2 = ninf.v;
    for (int base = 0; base < d; base += 64) {
        int cntc = min(64, d - base);
        if (lane < cntc) sl[w][lane] = ssrc[o + base + lane];
        int e = 0;
        for (; e + 8 <= cntc; e += 8) {
            unsigned s0 = sl[w][e + 0], s1 = sl[w][e + 1], s2 = sl[w][e + 2], s3 = sl[w][e + 3];
            unsigned s4 = sl[w][e + 4], s5 = sl[w][e + 5], s6 = sl[w][e + 6], s7 = sl[w][e + 7];
            h2 v0 = Cc[s0 * 64 + lane];
            h2 v1 = Cc[s1 * 64 + lane];
            h2 v2 = Cc[s2 * 64 + lane];
            h2 v3 = Cc[s3 * 64 + lane];
            h2 v4 = Cc[s4 * 64 + lane];
            h2 v5 = Cc[s5 * 64 + lane];
            h2 v6 = Cc[s6 * 64 + lane];
            h2 v7 = Cc[s7 * 64 + lane];
            h2 a0 = __builtin_elementwise_max(v0, v1);
            h2 a1 = __builtin_elementwise_max(v2, v3);
            h2 a2 = __builtin_elementwise_max(v4, v5);
            h2 a3 = __builtin_elementwise_max(v6, v7);
            h2 b0 = __builtin_elementwise_max(a0, a1);
            h2 b1 = __builtin_elementwise_max(a2, a3);
            m2 = __builtin_elementwise_max(m2, __builtin_elementwise_max(b0, b1));
        }
        if (e + 4 <= cntc) {
            unsigned s0 = sl[w][e + 0], s1 = sl[w][e + 1], s2 = sl[w][e + 2], s3 = sl[w][e + 3];
            h2 v0 = Cc[s0 * 64 + lane];
            h2 v1 = Cc[s1 * 64 + lane];
            h2 v2 = Cc[s2 * 64 + lane];
            h2 v3 = Cc[s3 * 64 + lane];
            h2 a0 = __builtin_elementwise_max(v0, v1);
            h2 a1 = __builtin_elementwise_max(v2, v3);
            m2 = __builtin_elementwise_max(m2, __builtin_elementwise_max(a0, a1));
            e += 4;
        }
        for (; e < cntc; ++e)
            m2 = __builtin_elementwise_max(m2, Cc[sl[w][e] * 64 + lane]);
    }
    float2 a = *(const float2*)&A[i * HDIM + lane * 2];
    float hx = (d > 0) ? fmaxf(a.x + (float)m2.x, 0.f) : 0.f;
    float hy = (d > 0) ? fmaxf(a.y + (float)m2.y, 0.f) : 0.f;
    H[i * 64 + lane] = h2{(_Float16)hx, (_Float16)hy};
}

// ---------------- BN stats over fp16 h: 196 blocks, fp32 accumulate --------------
__global__ __launch_bounds__(256) void k_stats(const _Float16* __restrict__ H,
                                               float* __restrict__ sums) {  // zeroed, padded
    __shared__ float4 ls[256], ls2[256];
    int t = threadIdx.x;
    int c4 = t & 31, rg = t >> 5;
    int row0 = blockIdx.x * 256;
    float4 s = make_float4(0.f, 0.f, 0.f, 0.f);
    float4 s2 = make_float4(0.f, 0.f, 0.f, 0.f);
#pragma unroll 4
    for (int it = 0; it < 32; ++it) {
        int row = row0 + rg * 32 + it;
        if (row < N_NODES) {
            h4 hv = *(const h4*)&H[row * HDIM + c4 * 4];
            float4 v = make_float4((float)hv.x, (float)hv.y, (float)hv.z, (float)hv.w);
            s.x += v.x; s.y += v.y; s.z += v.z; s.w += v.w;
            s2.x += v.x * v.x; s2.y += v.y * v.y; s2.z += v.z * v.z; s2.w += v.w * v.w;
        }
    }
    ls[t] = s; ls2[t] = s2;
    __syncthreads();
    if (t < 32) {
        float4 a = ls[t], a2 = ls2[t];
#pragma unroll
        for (int j = 1; j < 8; ++j) {
            float4 b = ls[j * 32 + t], b2 = ls2[j * 32 + t];
            a.x += b.x; a.y += b.y; a.z += b.z; a.w += b.w;
            a2.x += b2.x; a2.y += b2.y; a2.z += b2.z; a2.w += b2.w;
        }
        int c = t * 4;
        atomicAdd(&sums[(c + 0) * SSTR], a.x);
        atomicAdd(&sums[(c + 1) * SSTR], a.y);
        atomicAdd(&sums[(c + 2) * SSTR], a.z);
        atomicAdd(&sums[(c + 3) * SSTR], a.w);
        atomicAdd(&sums[(128 + c + 0) * SSTR], a2.x);
        atomicAdd(&sums[(128 + c + 1) * SSTR], a2.y);
        atomicAdd(&sums[(128 + c + 2) * SSTR], a2.z);
        atomicAdd(&sums[(128 + c + 3) * SSTR], a2.w);
    }
}

// ---------------- per-graph sums + layer-3 BN stats in ONE h pass ----------------
__global__ __launch_bounds__(128) void k_poolsum(const _Float16* __restrict__ H,
                                                 float* __restrict__ Pg,     // [100][128]
                                                 float* __restrict__ sums) { // zeroed, padded
    int g = blockIdx.x;
    int k = threadIdx.x;
    const _Float16* base = H + (size_t)g * ROWS_PER_GRAPH * HDIM;
    float s = 0.f, s2 = 0.f;
#pragma unroll 4
    for (int r = 0; r < ROWS_PER_GRAPH; ++r) {
        float v = (float)base[r * HDIM + k];
        s += v; s2 += v * v;
    }
    Pg[g * HDIM + k] = s;
    atomicAdd(&sums[k * SSTR], s);
    atomicAdd(&sums[(128 + k) * SSTR], s2);
}

// ---------------- final: BN3 (from sums) + linear + relu, 1 block/graph ----------
__global__ __launch_bounds__(128) void k_out(const float* __restrict__ Pg,
                                             const float* __restrict__ sums,
                                             const float* __restrict__ g3,
                                             const float* __restrict__ be3,
                                             const float* __restrict__ Wl,
                                             const float* __restrict__ bl,
                                             float* __restrict__ out) {
    int g = blockIdx.x;
    int k = threadIdx.x;
    float S  = sums[k * SSTR];
    float S2 = sums[(128 + k) * SSTR];
    float mean = S / (float)N_NODES;
    float var = fmaxf(S2 / (float)N_NODES - mean * mean, 0.f);
    float scv = g3[k] / sqrtf(var + BN_EPS);
    float shv = be3[k] - mean * scv;
    float p = (scv * (Pg[g * HDIM + k] * (1.f / (float)ROWS_PER_GRAPH)) + shv) * Wl[k];
    __shared__ float red[2];
    for (int o = 32; o > 0; o >>= 1) p += __shfl_down(p, o);
    if ((k & 63) == 0) red[k >> 6] = p;
    __syncthreads();
    if (k == 0) out[g] = fmaxf(red[0] + red[1] + bl[0], 0.f);
}

// ---------------- launcher --------------------------------------------------------
extern "C" void kernel_launch(void* const* d_in, const int* in_sizes, int n_in,
                              void* d_out, int out_size, void* d_ws, size_t ws_size,
                              hipStream_t stream) {
    const float* x   = (const float*)d_in[0];
    const int* ei    = (const int*)d_in[1];
    const float* W1  = (const float*)d_in[3];
    const float* b1  = (const float*)d_in[4];
    const float* W2  = (const float*)d_in[5];
    const float* b2  = (const float*)d_in[6];
    const float* W3  = (const float*)d_in[7];
    const float* b3  = (const float*)d_in[8];
    const float* g1  = (const float*)d_in[9];
    const float* be1 = (const float*)d_in[10];
    const float* g2  = (const float*)d_in[11];
    const float* be2 = (const float*)d_in[12];
    const float* g3  = (const float*)d_in[13];
    const float* be3 = (const float*)d_in[14];
    const float* Wl  = (const float*)d_in[15];
    const float* bl  = (const float*)d_in[16];
    float* out = (float*)d_out;

    const int* srcp = ei;
    const int* dstp = ei + N_EDGES;

    // ---- workspace carve-up (256B aligned) ----
    char* ws = (char*)d_ws;
    size_t o = 0;
    auto alloc = [&](size_t bytes) -> void* {
        o = (o + 255) & ~(size_t)255;
        void* p = ws + o;
        o += bytes;
        return p;
    };
    float* A      = (float*)alloc((size_t)N_NODES * HDIM * 4);
    _Float16* C   = (_Float16*)alloc((size_t)N_NODES * HDIM * 2);
    _Float16* h   = (_Float16*)alloc((size_t)N_NODES * HDIM * 2);
    float* Wcat1  = (float*)alloc((size_t)F_IN * 256 * 4);
    _Float16* Wf2 = (_Float16*)alloc((size_t)2 * 16384 * 2);
    _Float16* Wf3 = (_Float16*)alloc((size_t)2 * 16384 * 2);
    // ---- zeroed region: deg .. sums (single memset) ----
    unsigned* deg  = (unsigned*)alloc((size_t)N_NODES * 4);
    unsigned* bsum = (unsigned*)alloc((size_t)NBLK * 4);
    float* sums    = (float*)alloc((size_t)3 * SUMS_PER_LAYER * 4);  // 96 KB padded
    // ---- not zeroed (fully overwritten before read) ----
    unsigned* off  = (unsigned*)alloc((size_t)N_NODES * 4);
    unsigned* rank = (unsigned*)alloc((size_t)N_EDGES * 4);
    unsigned* ssrc = (unsigned*)alloc((size_t)N_EDGES * 4);
    float* Pg      = (float*)alloc((size_t)N_GRAPHS * HDIM * 4);
    (void)ws_size; (void)n_in; (void)in_sizes; (void)out_size;

    float* sums0 = sums;
    float* sums1 = sums + SUMS_PER_LAYER;
    float* sums2 = sums + 2 * SUMS_PER_LAYER;

    size_t zlen = (size_t)((char*)(sums + 3 * SUMS_PER_LAYER) - (char*)deg);
    (void)hipMemsetAsync(deg, 0, zlen, stream);                        // 1

    k_pre<<<PREP_BLKS + HIST_BLKS, 256, 0, stream>>>(W1, W2, W3, Wcat1, Wf2, Wf3,
                                                     dstp, deg, rank); // 2
    k_scanall<<<NBLK, 256, 0, stream>>>(deg, bsum, off);               // 3
    k_scatter<<<HIST_BLKS, 256, 0, stream>>>(srcp, dstp, off, rank, ssrc); // 4

    const dim3 MMG(MM_GRID, 2);
    const int AGB = N_NODES / 4;

    // layer 1
    k_mm1<F_IN, F_IN><<<MMG, 256, 0, stream>>>(x, Wcat1, b1, A, C);                 // 5
    k_agg<<<AGB, 256, 0, stream>>>(A, (const h2*)C, off, deg, ssrc, (h2*)h);        // 6
    k_stats<<<STATS_BLKS, 256, 0, stream>>>(h, sums0);                              // 7

    // layer 2 (MFMA, BN1 derived in-block from sums0)
    k_mmf<<<MMG, 256, 0, stream>>>(h, Wf2, b2, sums0, g1, be1, A, C);               // 8
    k_agg<<<AGB, 256, 0, stream>>>(A, (const h2*)C, off, deg, ssrc, (h2*)h);        // 9
    k_stats<<<STATS_BLKS, 256, 0, stream>>>(h, sums1);                              // 10

    // layer 3 (MFMA, BN2 derived in-block from sums1)
    k_mmf<<<MMG, 256, 0, stream>>>(h, Wf3, b3, sums1, g2, be2, A, C);               // 11
    k_agg<<<AGB, 256, 0, stream>>>(A, (const h2*)C, off, deg, ssrc, (h2*)h);        // 12

    // per-graph pool sums + layer-3 stats in one h pass, then per-graph output
    k_poolsum<<<N_GRAPHS, 128, 0, stream>>>(h, Pg, sums2);                          // 13
    k_out<<<N_GRAPHS, 128, 0, stream>>>(Pg, sums2, g3, be3, Wl, bl, out);           // 14
}